// Round 5
// baseline (171.831 us; speedup 1.0000x reference)
//
#include <hip/hip_runtime.h>
#include <math.h>

#define IMG_H 4096
#define IMG_W 4096
#define RPT 8                 // rows per wave
#define WPR (IMG_W / 256)     // waves per row strip: each wave spans 256 cols

typedef float floatx4 __attribute__((ext_vector_type(4)));  // native vec for nontemporal builtins

// Quantize angle exactly like the reference float32 path; pick the two
// neighbors branchlessly; emit img if local-max & interior.
__device__ __forceinline__ float nms_px(float t, bool interior,
                                        float uL, float uC, float uR,
                                        float cL, float cC, float cR,
                                        float dL, float dC, float dR) {
    float deg = t * 57.29577951308232f;        // float32(180/pi)
    deg = (deg < 0.0f) ? deg + 180.0f : deg;
    float q = rintf(deg / 45.0f) * 45.0f;      // IEEE div + round-half-even
    const bool is0  = (q == 0.0f) || (q == 180.0f);
    const bool is45 = (q == 45.0f);
    const bool is90 = (q == 90.0f);
    const float a = is0 ? cR : (is45 ? dR : (is90 ? dC : dL));
    const float b = is0 ? cL : (is45 ? uL : (is90 ? uC : uR));
    return ((cC >= a) && (cC >= b) && interior) ? cC : 0.0f;
}

// One wave = 256 contiguous cols x RPT rows. Horizontal neighbors via wave
// shuffles (no strided gathers); only lanes 0/63 fetch the wave-boundary
// column with a 2-line predicated scalar load. Next row's data is prefetched
// while the current row computes.
__global__ __launch_bounds__(256) void nms_kernel(const float* __restrict__ img,
                                                  const float* __restrict__ theta,
                                                  float* __restrict__ out) {
    const int gtid = blockIdx.x * 256 + threadIdx.x;
    const int wave = gtid >> 6;
    const int lane = gtid & 63;
    const int g  = wave / WPR;          // row-group index
    const int wc = (wave % WPR) << 8;   // wave's first column
    const int y4 = wc + (lane << 2);    // this lane's 4-px chunk
    const int x0 = g * RPT;

    const bool is_l = (lane == 0);
    const bool is_r = (lane == 63);
    const bool edge_lane = is_l || is_r;
    // the single boundary column this lane would fetch (clamped; border px output 0)
    const int ye = is_l ? (wc > 0 ? wc - 1 : 0)
                        : (wc + 256 < IMG_W ? wc + 256 : IMG_W - 1);

    // col-interior flags (per-lane constants)
    const bool c0_int = (y4 > 0);
    const bool c3_int = (y4 + 4 < IMG_W);

    auto load_row = [&](int x, floatx4& v, float& e) {
        const float* __restrict__ pr = img + (size_t)x * IMG_W;
        v = *(const floatx4*)(pr + y4);
        e = 0.0f;
        if (edge_lane) e = pr[ye];      // 2 active lanes, 2 cache lines
    };

    floatx4 u, c, d, d_nxt;
    float ue, ce, de, de_nxt;
    floatx4 th, th_nxt;

    load_row((x0 > 0) ? x0 - 1 : 0, u, ue);
    load_row(x0, c, ce);
    load_row((x0 + 1 < IMG_H) ? x0 + 1 : IMG_H - 1, d, de);
    th = *(const floatx4*)(theta + (size_t)x0 * IMG_W + y4);

    #pragma unroll
    for (int i = 0; i < RPT; ++i) {
        const int x = x0 + i;

        // ---- prefetch next row while this row computes ----
        if (i < RPT - 1) {
            const int xn = (x + 2 < IMG_H) ? x + 2 : IMG_H - 1;
            load_row(xn, d_nxt, de_nxt);
            const float* tp = theta + (size_t)(x + 1) * IMG_W + y4;
            th_nxt = __builtin_nontemporal_load((const floatx4*)tp);
        }

        // ---- horizontal neighbors via shuffles ----
        float uLs = __shfl_up(u.w, 1, 64), uRs = __shfl_down(u.x, 1, 64);
        float cLs = __shfl_up(c.w, 1, 64), cRs = __shfl_down(c.x, 1, 64);
        float dLs = __shfl_up(d.w, 1, 64), dRs = __shfl_down(d.x, 1, 64);
        const float uL = is_l ? ue : uLs, uR = is_r ? ue : uRs;
        const float cL = is_l ? ce : cLs, cR = is_r ? ce : cRs;
        const float dL = is_l ? de : dLs, dR = is_r ? de : dRs;

        const bool row_int = (x > 0) && (x < IMG_H - 1);

        floatx4 o;
        o.x = nms_px(th.x, row_int && c0_int, uL,  u.x, u.y,  cL,  c.x, c.y,  dL,  d.x, d.y);
        o.y = nms_px(th.y, row_int,           u.x, u.y, u.z,  c.x, c.y, c.z,  d.x, d.y, d.z);
        o.z = nms_px(th.z, row_int,           u.y, u.z, u.w,  c.y, c.z, c.w,  d.y, d.z, d.w);
        o.w = nms_px(th.w, row_int && c3_int, u.z, u.w, uR,   c.z, c.w, cR,   d.z, d.w, dR);

        floatx4* po = (floatx4*)(out + (size_t)x * IMG_W + y4);
        __builtin_nontemporal_store(o, po);

        // slide the window
        u = c; ue = ce;
        c = d; ce = de;
        d = d_nxt; de = de_nxt;
        th = th_nxt;
    }
}

extern "C" void kernel_launch(void* const* d_in, const int* in_sizes, int n_in,
                              void* d_out, int out_size, void* d_ws, size_t ws_size,
                              hipStream_t stream) {
    const float* img   = (const float*)d_in[0];
    const float* theta = (const float*)d_in[1];
    float* out = (float*)d_out;

    const int total_threads = (IMG_H / RPT) * WPR * 64;  // 512 * 16 * 64
    const int block = 256;
    const int grid = total_threads / block;               // 2048
    nms_kernel<<<grid, block, 0, stream>>>(img, theta, out);
}